// Round 13
// baseline (137.593 us; speedup 1.0000x reference)
//
#include <hip/hip_runtime.h>
#include <hip/hip_bf16.h>

#define QUERY_DIM 128
#define HIDDEN 128

typedef float f32x4 __attribute__((ext_vector_type(4)));

__device__ __forceinline__ float dot4(f32x4 a, f32x4 b) {
    return a.x * b.x + a.y * b.y + a.z * b.z + a.w * b.w;
}

// ---------------------------------------------------------------------------
// Kernel 1: W[e][d] = sum_h WQ[h][e] * WK[h][d]   (128x128 = 64KB, tiny)
// ---------------------------------------------------------------------------
__global__ void wqk_kernel(const float* __restrict__ WQ,
                           const float* __restrict__ WK,
                           float* __restrict__ W) {
    int e = blockIdx.x;    // 0..127
    int d = threadIdx.x;   // 0..127
    float acc = 0.f;
#pragma unroll 8
    for (int h = 0; h < HIDDEN; ++h) {
        acc += WQ[h * QUERY_DIM + e] * WK[h * 128 + d];
    }
    W[e * 128 + d] = acc;
}

// ---------------------------------------------------------------------------
// Kernel 2 (uber): block b owns segments 8b..8b+7. Fully block-independent:
//  (S) threads 0..8 binary-search the 9 segment boundaries (idx sorted);
//      waves 1-3 proceed with staging meanwhile.
//  (A) in-block qproj of the block's 8 R rows: thread (r=t>>5, c4=(t&31)*4);
//      q from LDS broadcast, W from L2 GLOBAL — lanes 0..31 read consecutive
//      c4 -> coalesced 512B/instr; unique W bytes/block = 64KB (L2-hot,
//      128MB aggregate ~4us). acc -> LDS rbuf (reuses ql). No R in HBM,
//      no 64KB-LDS occupancy trap (total LDS = 4KB), no per-wave W
//      amplification (reuse is per-block).
//  (B) stream: wave wv owns local segments 2wv, 2wv+1 (contiguous K);
//      R7-proven pipeline: x4-unrolled 1KB wave-loads, running max,
//      vmcnt fence, sum-exp, weights from L1-hot scores.
// ---------------------------------------------------------------------------
__global__ void uber_kernel(const float* __restrict__ Q,
                            const float* __restrict__ W,
                            const float* __restrict__ K,
                            const int* __restrict__ idx,
                            float* __restrict__ weights,
                            float* scores,   // no restrict: store+load alias
                            int nmols, int total) {
    __shared__ float ql[8 * 128];   // 4KB: Q rows, then R rows (rbuf)
    __shared__ int   segb[9];
    const int t = threadIdx.x;
    const long row0 = (long)blockIdx.x * 8;   // first segment of this block

    // ---- (S) segment boundaries ----
    if (t < 9) {
        long m = row0 + t;
        if (m >= nmols) {
            segb[t] = total;
        } else {
            int lo = 0, hi = total;
            while (lo < hi) {
                int mid = (lo + hi) >> 1;
                if (idx[mid] < (int)m) lo = mid + 1; else hi = mid;
            }
            segb[t] = lo;
        }
    }

    // ---- stage 8 Q rows (1024 floats = 256 thr x f32x4) ----
    {
        long qmax = (long)nmols * 128 - 4;
        long qoff = row0 * 128 + t * 4;
        if (qoff > qmax) qoff = qmax;     // clamp (tail blocks only)
        *(f32x4*)&ql[t * 4] = *(const f32x4*)&Q[qoff];
    }
    __syncthreads();

    // ---- (A) in-block qproj: 8 rows x 128 cols over 256 threads ----
    const int r  = t >> 5;           // row 0..7
    const int c4 = (t & 31) * 4;     // 4 contiguous cols
    f32x4 acc = {0.f, 0.f, 0.f, 0.f};
#pragma unroll 4
    for (int d = 0; d < 128; d += 4) {
        f32x4 q4 = *(const f32x4*)&ql[r * 128 + d];        // LDS broadcast
        f32x4 w0 = *(const f32x4*)&W[(d + 0) * 128 + c4];  // L2, coalesced
        f32x4 w1 = *(const f32x4*)&W[(d + 1) * 128 + c4];
        f32x4 w2 = *(const f32x4*)&W[(d + 2) * 128 + c4];
        f32x4 w3 = *(const f32x4*)&W[(d + 3) * 128 + c4];
        acc += q4.x * w0 + q4.y * w1 + q4.z * w2 + q4.w * w3;
    }
    __syncthreads();                       // all ql reads done
    *(f32x4*)&ql[r * 128 + c4] = acc;      // rbuf overwrites ql
    __syncthreads();                       // rbuf + segb ready

    // ---- (B) stream 2 segments per wave ----
    const int lane = t & 63;
    const int half = lane >> 5;      // 0/1
    const int hl = lane & 31;        // lane within half-wave
    const int wv = t >> 6;           // wave 0..3
    const float sc = 0.08838834764831845f;  // 1/sqrt(128)

    for (int si = 0; si < 2; ++si) {
        int ls = wv * 2 + si;                 // local segment 0..7
        long s = row0 + ls;
        if (s >= nmols) break;
        int s0 = segb[ls], s1 = segb[ls + 1];
        if (s0 >= s1) continue;

        f32x4 rfrag = *(const f32x4*)&ql[ls * 128 + hl * 4];

        // ---- phase 1: scores + running max (x4 unroll, 4KB/wave in flight)
        float mx = -__builtin_inff();
        int kb = s0;
        for (; kb + 8 <= s1; kb += 8) {
            long k = kb + half;          // this half: rows k, k+2, k+4, k+6
            f32x4 a0 = __builtin_nontemporal_load((const f32x4*)(K + (k + 0) * 128) + hl);
            f32x4 a1 = __builtin_nontemporal_load((const f32x4*)(K + (k + 2) * 128) + hl);
            f32x4 a2 = __builtin_nontemporal_load((const f32x4*)(K + (k + 4) * 128) + hl);
            f32x4 a3 = __builtin_nontemporal_load((const f32x4*)(K + (k + 6) * 128) + hl);
            float v0 = dot4(a0, rfrag);
            float v1 = dot4(a1, rfrag);
            float v2 = dot4(a2, rfrag);
            float v3 = dot4(a3, rfrag);
#pragma unroll
            for (int off = 16; off > 0; off >>= 1) {
                v0 += __shfl_xor(v0, off, 64);
                v1 += __shfl_xor(v1, off, 64);
                v2 += __shfl_xor(v2, off, 64);
                v3 += __shfl_xor(v3, off, 64);
            }
            v0 *= sc; v1 *= sc; v2 *= sc; v3 *= sc;
            if (hl == 0) {
                scores[k + 0] = v0;
                scores[k + 2] = v1;
                scores[k + 4] = v2;
                scores[k + 6] = v3;
            }
            mx = fmaxf(mx, fmaxf(fmaxf(v0, v1), fmaxf(v2, v3)));
        }
        for (long k = kb + half; k < s1; k += 2) {   // tail (<8 keys)
            f32x4 kv = __builtin_nontemporal_load((const f32x4*)(K + k * 128) + hl);
            float v = dot4(kv, rfrag);
#pragma unroll
            for (int off = 16; off > 0; off >>= 1) v += __shfl_xor(v, off, 64);
            v *= sc;
            if (hl == 0) scores[k] = v;
            mx = fmaxf(mx, v);
        }
        mx = fmaxf(mx, __shfl_xor(mx, 32, 64));

        // make this wave's score stores visible before re-reading
        asm volatile("s_waitcnt vmcnt(0)" ::: "memory");

        // ---- phase 2: sum of exp (scores L1-hot) ----
        float sum = 0.f;
        for (int i = s0 + lane; i < s1; i += 64) sum += __expf(scores[i] - mx);
#pragma unroll
        for (int off = 32; off > 0; off >>= 1) sum += __shfl_xor(sum, off, 64);
        float inv = 1.0f / sum;

        // ---- phase 3: weights ----
        for (int i = s0 + lane; i < s1; i += 64)
            weights[i] = __expf(scores[i] - mx) * inv;
    }
}

// ---------------------------------------------------------------------------
extern "C" void kernel_launch(void* const* d_in, const int* in_sizes, int n_in,
                              void* d_out, int out_size, void* d_ws, size_t ws_size,
                              hipStream_t stream) {
    const float* Q   = (const float*)d_in[0];
    const float* K   = (const float*)d_in[1];
    const float* WQ  = (const float*)d_in[2];
    const float* WK  = (const float*)d_in[3];
    const int*   idx = (const int*)d_in[4];

    const int nmols = in_sizes[0] / QUERY_DIM;   // 16384
    const int total = in_sizes[4];               // 1048576

    float* weights = (float*)d_out;              // output 0
    float* scores  = (float*)d_out + total;      // output 1

    float* W = (float*)d_ws;                     // 64 KB scratch

    wqk_kernel<<<128, 128, 0, stream>>>(WQ, WK, W);
    int blocks = (nmols + 7) / 8;                // 2048
    uber_kernel<<<blocks, 256, 0, stream>>>(Q, W, K, idx, weights, scores, nmols, total);
}

// Round 14
// 130.579 us; speedup vs baseline: 1.0537x; 1.0537x over previous
//
#include <hip/hip_runtime.h>
#include <hip/hip_bf16.h>

#define QUERY_DIM 128
#define HIDDEN 128

typedef float f32x4 __attribute__((ext_vector_type(4)));

__device__ __forceinline__ float dot4(f32x4 a, f32x4 b) {
    return a.x * b.x + a.y * b.y + a.z * b.z + a.w * b.w;
}

// ---------------------------------------------------------------------------
// Kernel 1: W[e][d] = sum_h WQ[h][e] * WK[h][d]   (128x128, tiny)
// ---------------------------------------------------------------------------
__global__ void wqk_kernel(const float* __restrict__ WQ,
                           const float* __restrict__ WK,
                           float* __restrict__ W) {
    int e = blockIdx.x;    // 0..127
    int d = threadIdx.x;   // 0..127
    float acc = 0.f;
#pragma unroll 8
    for (int h = 0; h < HIDDEN; ++h) {
        acc += WQ[h * QUERY_DIM + e] * WK[h * 128 + d];
    }
    W[e * 128 + d] = acc;
}

// ---------------------------------------------------------------------------
// Kernel 2 (qproj2 + segstart): blocks [0, qblocks) do R = Q @ W with
// 8-row x 4-col register blocking: 64 rows/block, thread t owns cols
// [4*(t&31), +4) for rows [8*(t>>5), +8). Per 4-d tile: 4 b128 W reads
// (per-lane) + 8 b128 Q reads (half-wave broadcast, free) = 1.5 B/FMA of
// LDS traffic. Blocks [qblocks, ...) do segment-start binary search.
// ---------------------------------------------------------------------------
__global__ __launch_bounds__(256) void qproj2_kernel(const float* __restrict__ Q,
                                                     const float* __restrict__ W,
                                                     float* __restrict__ R,
                                                     const int* __restrict__ idx,
                                                     int* __restrict__ start,
                                                     int nmols, int total, int qblocks) {
    int b = blockIdx.x;
    int t = threadIdx.x;
    if (b >= qblocks) {
        // ---- segment starts via binary search (idx sorted) ----
        int m = (b - qblocks) * 256 + t;
        if (m > nmols) return;
        if (m == nmols) { start[m] = total; return; }
        int lo = 0, hi = total;
        while (lo < hi) {
            int mid = (lo + hi) >> 1;
            if (idx[mid] < m) lo = mid + 1; else hi = mid;
        }
        start[m] = lo;
        return;
    }

    __shared__ float wl[64 * 128];   // 32 KB: half of W
    __shared__ float ql[64 * 128];   // 32 KB: 64 Q rows
    const int c4 = (t & 31) * 4;     // 4 contiguous columns
    const int g  = t >> 5;           // row-group: rows g*8 .. g*8+7
    const long row0 = (long)b * 64;

    // stage 64 Q rows (8192 floats, clamped for generality)
    for (int i = t * 4; i < 64 * 128; i += 256 * 4) {
        long rr = row0 + (i >> 7);
        if (rr > nmols - 1) rr = nmols - 1;
        *(f32x4*)&ql[i] = *(const f32x4*)&Q[rr * 128 + (i & 127)];
    }

    f32x4 acc[8];
#pragma unroll
    for (int r = 0; r < 8; ++r) acc[r] = (f32x4){0.f, 0.f, 0.f, 0.f};

    for (int hf = 0; hf < 2; ++hf) {
        __syncthreads();
        for (int i = t * 4; i < 64 * 128; i += 256 * 4) {
            *(f32x4*)&wl[i] = *(const f32x4*)&W[hf * 64 * 128 + i];
        }
        __syncthreads();
        for (int d = 0; d < 64; d += 4) {
            f32x4 w0 = *(const f32x4*)&wl[(d + 0) * 128 + c4];
            f32x4 w1 = *(const f32x4*)&wl[(d + 1) * 128 + c4];
            f32x4 w2 = *(const f32x4*)&wl[(d + 2) * 128 + c4];
            f32x4 w3 = *(const f32x4*)&wl[(d + 3) * 128 + c4];
            int dg = hf * 64 + d;
#pragma unroll
            for (int r = 0; r < 8; ++r) {
                f32x4 q = *(const f32x4*)&ql[(g * 8 + r) * 128 + dg];  // broadcast
                acc[r] += q.x * w0 + q.y * w1 + q.z * w2 + q.w * w3;
            }
        }
    }
#pragma unroll
    for (int r = 0; r < 8; ++r) {
        long row = row0 + g * 8 + r;
        if (row < nmols) *(f32x4*)&R[row * 128 + c4] = acc[r];
    }
}

// ---------------------------------------------------------------------------
// Kernel 3 (fused, dominant) — R7 version verbatim.
// One wave per segment (grid-stride); half-wave per key row (512B);
// phase 1 unrolled x4 (4 independent 1KB wave-loads in flight).
// ---------------------------------------------------------------------------
__global__ __launch_bounds__(256) void fused_kernel(const float* __restrict__ K,
                                                    const float* __restrict__ R,
                                                    const int* __restrict__ start,
                                                    float* __restrict__ weights,
                                                    float* scores,   // no restrict: store+load alias
                                                    int nmols) {
    const int lane = threadIdx.x & 63;
    const int half = lane >> 5;      // 0/1
    const int hl = lane & 31;        // lane within half-wave
    const int wave = (blockIdx.x * 256 + threadIdx.x) >> 6;
    const int nwaves = gridDim.x * 4;
    const float sc = 0.08838834764831845f;  // 1/sqrt(128)

    for (int s = wave; s < nmols; s += nwaves) {
        int s0 = start[s], s1 = start[s + 1];
        if (s0 >= s1) continue;

        f32x4 rfrag = *((const f32x4*)(R + (long)s * 128) + hl);

        // ---- phase 1: scores + running max ----
        float mx = -__builtin_inff();
        int kb = s0;
        for (; kb + 8 <= s1; kb += 8) {
            long k = kb + half;          // this half: rows k, k+2, k+4, k+6
            const f32x4* p0 = (const f32x4*)(K + (k + 0) * 128) + hl;
            const f32x4* p1 = (const f32x4*)(K + (k + 2) * 128) + hl;
            const f32x4* p2 = (const f32x4*)(K + (k + 4) * 128) + hl;
            const f32x4* p3 = (const f32x4*)(K + (k + 6) * 128) + hl;
            f32x4 a0 = __builtin_nontemporal_load(p0);
            f32x4 a1 = __builtin_nontemporal_load(p1);
            f32x4 a2 = __builtin_nontemporal_load(p2);
            f32x4 a3 = __builtin_nontemporal_load(p3);
            float v0 = dot4(a0, rfrag);
            float v1 = dot4(a1, rfrag);
            float v2 = dot4(a2, rfrag);
            float v3 = dot4(a3, rfrag);
#pragma unroll
            for (int off = 16; off > 0; off >>= 1) {
                v0 += __shfl_xor(v0, off, 64);
                v1 += __shfl_xor(v1, off, 64);
                v2 += __shfl_xor(v2, off, 64);
                v3 += __shfl_xor(v3, off, 64);
            }
            v0 *= sc; v1 *= sc; v2 *= sc; v3 *= sc;
            if (hl == 0) {
                scores[k + 0] = v0;
                scores[k + 2] = v1;
                scores[k + 4] = v2;
                scores[k + 6] = v3;
            }
            mx = fmaxf(mx, fmaxf(fmaxf(v0, v1), fmaxf(v2, v3)));
        }
        for (long k = kb + half; k < s1; k += 2) {   // tail (<8 keys)
            f32x4 kv = __builtin_nontemporal_load((const f32x4*)(K + k * 128) + hl);
            float v = dot4(kv, rfrag);
#pragma unroll
            for (int off = 16; off > 0; off >>= 1) v += __shfl_xor(v, off, 64);
            v *= sc;
            if (hl == 0) scores[k] = v;
            mx = fmaxf(mx, v);
        }
        mx = fmaxf(mx, __shfl_xor(mx, 32, 64));

        // make the scores stores visible before re-reading
        asm volatile("s_waitcnt vmcnt(0)" ::: "memory");

        // ---- phase 2: sum of exp (scores L1-hot) ----
        float sum = 0.f;
        for (int i = s0 + lane; i < s1; i += 64) sum += __expf(scores[i] - mx);
#pragma unroll
        for (int off = 32; off > 0; off >>= 1) sum += __shfl_xor(sum, off, 64);
        float inv = 1.0f / sum;

        // ---- phase 3: weights ----
        for (int i = s0 + lane; i < s1; i += 64)
            weights[i] = __expf(scores[i] - mx) * inv;
    }
}

// ---------------------------------------------------------------------------
extern "C" void kernel_launch(void* const* d_in, const int* in_sizes, int n_in,
                              void* d_out, int out_size, void* d_ws, size_t ws_size,
                              hipStream_t stream) {
    const float* Q   = (const float*)d_in[0];
    const float* K   = (const float*)d_in[1];
    const float* WQ  = (const float*)d_in[2];
    const float* WK  = (const float*)d_in[3];
    const int*   idx = (const int*)d_in[4];

    const int nmols = in_sizes[0] / QUERY_DIM;   // 16384
    const int total = in_sizes[4];               // 1048576

    float* weights = (float*)d_out;              // output 0
    float* scores  = (float*)d_out + total;      // output 1

    char* ws = (char*)d_ws;
    float* W        = (float*)ws;                        // 64 KB
    int*   segstart = (int*)(ws + 65536);                // (nmols+1)*4
    float* R        = (float*)(ws + 65536 + 131072);     // nmols*128*4 = 8 MB

    wqk_kernel<<<128, 128, 0, stream>>>(WQ, WK, W);
    int qblocks  = (nmols + 63) / 64;            // 256
    int segblocks = (nmols + 1 + 255) / 256;     // 65
    qproj2_kernel<<<qblocks + segblocks, 256, 0, stream>>>(Q, W, R, idx, segstart,
                                                           nmols, total, qblocks);
    fused_kernel<<<2048, 256, 0, stream>>>(K, R, segstart, weights, scores, nmols);
}